// Round 2
// baseline (290.329 us; speedup 1.0000x reference)
//
#include <hip/hip_runtime.h>
#include <hip/hip_bf16.h>
#include <hip/hip_fp16.h>

// SpatialAttention: B=32, C=273, T=3000, O=270, D=2048. fp32 in, fp32 out.
#define NB 32
#define NC 273
#define NT 3000
#define NO 270
#define ND 2048
#define CP 288  // C padded to 9*32 for out-GEMM K dimension

typedef _Float16 f16x8 __attribute__((ext_vector_type(8)));
typedef float f32x4 __attribute__((ext_vector_type(4)));

// Workspace layout (bytes):
//   [55296000, 64,730,880)  scores float   [NB][NO][NC]
//   [64730880, 69,707,520)  W     _Float16 [NB][NO][CP]  (softmaxed weights, zero-padded)
//   [69707520, 70,813,440)  headsh _Float16 [NO][ND]
// (X^T eliminated this round; offsets kept stable.)
#define S_OFF 55296000UL
#define W_OFF 64730880UL
#define H_OFF 69707520UL

// ---------------------------------------------------------------------------
// heads fp32 -> fp16. 270 blocks x 256 thr x 8 elems (exact).
// ---------------------------------------------------------------------------
__global__ void heads_cvt_kernel(const float* __restrict__ heads,
                                 _Float16* __restrict__ hh) {
  const size_t idx = ((size_t)blockIdx.x * 256 + threadIdx.x) * 8;
  const float4 a = *reinterpret_cast<const float4*>(heads + idx);
  const float4 c = *reinterpret_cast<const float4*>(heads + idx + 4);
  f16x8 v;
  v[0] = (_Float16)a.x; v[1] = (_Float16)a.y; v[2] = (_Float16)a.z; v[3] = (_Float16)a.w;
  v[4] = (_Float16)c.x; v[5] = (_Float16)c.y; v[6] = (_Float16)c.z; v[7] = (_Float16)c.w;
  *reinterpret_cast<f16x8*>(hh + idx) = v;
}

// ---------------------------------------------------------------------------
// scores[b,o,c] = sum_d heads[o,d]*emb[b,c,d], with the emb B-tile GENERATED
// in-register (phase naturally in revolutions -> fract + v_sin; cos folded
// as +0.25 rev). Tile 64(o) x 64(c), K-step 64, 4 waves 2x2.
// grid = 800 (5 c-tiles x 5 o-tiles x 32 b)
// ---------------------------------------------------------------------------
__global__ void scores_kernel(const _Float16* __restrict__ hh,
                              const float* __restrict__ layout,
                              float* __restrict__ scores) {
  __shared__ _Float16 As[64][72];
  __shared__ _Float16 Bs[64][72];
  const int gid = blockIdx.x;
  const int tid = threadIdx.x;
  const int b = gid / 25;
  const int rem = gid % 25;
  const int o0 = (rem / 5) * 64;
  const int c0 = (rem % 5) * 64;
  const int lane = tid & 63, w = tid >> 6;
  const int wm = (w >> 1) * 32, wn = (w & 1) * 32;
  const int ln = lane & 15, quad = lane >> 4;
  const int sr = tid >> 2;        // staging row 0..63 (o for A, c for B)
  const int sk = (tid & 3) * 16;  // k-chunk offset (halves)

  // Per-thread channel position for B-tile generation.
  const int ch = c0 + sr;
  float px = 0.f, py = 0.f;
  if (ch < NC) {
    const float inv = 1.0f / 1.2f;
    const float* lp = layout + ((size_t)b * NC + ch) * 2;
    px = (lp[0] + 0.1f) * inv;
    py = (lp[1] + 0.1f) * inv;
  }

  f32x4 acc[2][2] = {};

  for (int k0 = 0; k0 < ND; k0 += 64) {
    {  // A-tile staging (heads fp16, L2-resident)
      const int o = o0 + sr;
      uint4 u0 = {0, 0, 0, 0}, u1 = {0, 0, 0, 0};
      if (o < NO) {
        const uint4* p = reinterpret_cast<const uint4*>(hh + (size_t)o * ND + k0 + sk);
        u0 = p[0]; u1 = p[1];
      }
      *reinterpret_cast<uint4*>(&As[sr][sk]) = u0;
      *reinterpret_cast<uint4*>(&As[sr][sk + 8]) = u1;
    }
    {  // B-tile generation: 16 consecutive k share i; base + py*s walks j.
      const int kg = k0 + sk;      // multiple of 16
      const int dd = kg & 1023;    // multiple of 16
      const float base = px * (float)(dd >> 5) + py * (float)(dd & 31)
                       + ((kg < 1024) ? 0.0f : 0.25f);
      f16x8 h0, h1;
#pragma unroll
      for (int s = 0; s < 8; ++s) {
        float ph = base + py * (float)s;
        ph -= floorf(ph);
        h0[s] = (_Float16)__builtin_amdgcn_sinf(ph);
      }
#pragma unroll
      for (int s = 0; s < 8; ++s) {
        float ph = base + py * (float)(s + 8);
        ph -= floorf(ph);
        h1[s] = (_Float16)__builtin_amdgcn_sinf(ph);
      }
      *reinterpret_cast<f16x8*>(&Bs[sr][sk]) = h0;
      *reinterpret_cast<f16x8*>(&Bs[sr][sk + 8]) = h1;
    }
    __syncthreads();
#pragma unroll
    for (int ks = 0; ks < 64; ks += 32) {
      const int kf = ks + quad * 8;
      const f16x8 a0 = *reinterpret_cast<const f16x8*>(&As[wm + ln][kf]);
      const f16x8 a1 = *reinterpret_cast<const f16x8*>(&As[wm + 16 + ln][kf]);
      const f16x8 b0 = *reinterpret_cast<const f16x8*>(&Bs[wn + ln][kf]);
      const f16x8 b1 = *reinterpret_cast<const f16x8*>(&Bs[wn + 16 + ln][kf]);
      acc[0][0] = __builtin_amdgcn_mfma_f32_16x16x32_f16(a0, b0, acc[0][0], 0, 0, 0);
      acc[0][1] = __builtin_amdgcn_mfma_f32_16x16x32_f16(a0, b1, acc[0][1], 0, 0, 0);
      acc[1][0] = __builtin_amdgcn_mfma_f32_16x16x32_f16(a1, b0, acc[1][0], 0, 0, 0);
      acc[1][1] = __builtin_amdgcn_mfma_f32_16x16x32_f16(a1, b1, acc[1][1], 0, 0, 0);
    }
    __syncthreads();
  }

  float* sB = scores + (size_t)b * NO * NC;
#pragma unroll
  for (int i = 0; i < 2; ++i) {
    const int ob = o0 + wm + 16 * i + quad * 4;
#pragma unroll
    for (int j = 0; j < 2; ++j) {
      const int cc = c0 + wn + 16 * j + ln;
      if (cc >= NC) continue;
#pragma unroll
      for (int r = 0; r < 4; ++r) {
        const int o = ob + r;
        if (o < NO) sB[(size_t)o * NC + cc] = acc[i][j][r];
      }
    }
  }
}

// ---------------------------------------------------------------------------
// Row softmax over C=273, fp32 in -> fp16 weights out, zero-padded to CP=288.
// One wave per (b,o) row. grid = 8640/4, block 256.
// ---------------------------------------------------------------------------
__global__ void softmax_kernel(const float* __restrict__ sc,
                               _Float16* __restrict__ wq) {
  const int row = blockIdx.x * 4 + (threadIdx.x >> 6);
  const int lane = threadIdx.x & 63;
  const float* p = sc + (size_t)row * NC;
  _Float16* q = wq + (size_t)row * CP;
  float v[5];
  float m = -3.0e38f;
#pragma unroll
  for (int k = 0; k < 5; ++k) {
    const int c = lane + k * 64;
    v[k] = (c < NC) ? p[c] : -3.0e38f;
    m = fmaxf(m, v[k]);
  }
#pragma unroll
  for (int off = 32; off > 0; off >>= 1) m = fmaxf(m, __shfl_xor(m, off));
  float s = 0.f;
#pragma unroll
  for (int k = 0; k < 5; ++k) {
    v[k] = expf(v[k] - m);
    s += v[k];
  }
#pragma unroll
  for (int off = 32; off > 0; off >>= 1) s += __shfl_xor(s, off);
  const float r = 1.0f / s;
#pragma unroll
  for (int k = 0; k < 5; ++k) {
    const int c = lane + k * 64;
    if (c < NC) q[c] = (_Float16)(v[k] * r);
    else if (c < CP) q[c] = (_Float16)0.f;
  }
}

// ---------------------------------------------------------------------------
// out[b,o,t] = sum_c W[b,o,c]*brain[b,c,t], brain read DIRECTLY (X^T never
// materialized). One block per (b, 64-t slab):
//   1) stage brain[b][:][t0:t0+64] -> LDS Bs[t][c] fp16 (transpose during
//      staging; coalesced float4 reads along t; c zero-padded to 288)
//   2) loop 5 o-tiles: stage W A-tile (L2-hot), 9 K-steps of MFMA, write out.
// B-slab resident across the whole o-loop => brain read exactly once.
// LDS 75.8 KB -> 2 blocks/CU. grid = (47 t-slabs, 32 b), x fastest so
// same-b blocks share W[b] in L2.
// ---------------------------------------------------------------------------
#define TS 64

__global__ void out_kernel(const _Float16* __restrict__ wq,
                           const float* __restrict__ brain,
                           float* __restrict__ out) {
  __shared__ _Float16 As[64][296];
  __shared__ _Float16 Bs[TS][296];
  const int b = blockIdx.y;
  const int t0 = blockIdx.x * TS;
  const int tid = threadIdx.x;
  const int lane = tid & 63, w = tid >> 6;
  const int wm = (w >> 1) * 32, wn = (w & 1) * 32;
  const int ln = lane & 15, quad = lane >> 4;

  // ---- stage Bs: transpose brain slab into [t][c] fp16, zero-pad c>=273 ----
  {
    const int cw = tid >> 4;         // 16 c-rows per pass
    const int tl = (tid & 15) * 4;   // 4 consecutive t per thread
#pragma unroll 6
    for (int p = 0; p < 18; ++p) {
      const int c = p * 16 + cw;
      float4 v = {0.f, 0.f, 0.f, 0.f};
      if (c < NC) {
        const int t = t0 + tl;
        const float* src = brain + ((size_t)b * NC + c) * NT + t;
        if (t + 3 < NT) {
          v = *reinterpret_cast<const float4*>(src);
        } else {
          if (t + 0 < NT) v.x = src[0];
          if (t + 1 < NT) v.y = src[1];
          if (t + 2 < NT) v.z = src[2];
        }
      }
      Bs[tl + 0][c] = (_Float16)v.x;
      Bs[tl + 1][c] = (_Float16)v.y;
      Bs[tl + 2][c] = (_Float16)v.z;
      Bs[tl + 3][c] = (_Float16)v.w;
    }
  }

  const _Float16* Wb = wq + (size_t)b * NO * CP;
  float* oB = out + (size_t)b * NO * NT;

  for (int ot = 0; ot < 5; ++ot) {
    const int o0 = ot * 64;
    // ---- stage As: W[b][o0:o0+64][0:288] (L2-resident) ----
    {
      const int row = tid >> 2;
      const int o = o0 + row;
#pragma unroll
      for (int k = 0; k < 9; ++k) {
        const int col = (tid & 3) * 8 + k * 32;
        uint4 u = {0, 0, 0, 0};
        if (o < NO) u = *reinterpret_cast<const uint4*>(Wb + (size_t)o * CP + col);
        *reinterpret_cast<uint4*>(&As[row][col]) = u;
      }
    }
    __syncthreads();  // As staged (first iter: also fences Bs staging)

    f32x4 acc[2][2] = {};
#pragma unroll
    for (int s = 0; s < 9; ++s) {
      const int kf = s * 32 + quad * 8;
      const f16x8 a0 = *reinterpret_cast<const f16x8*>(&As[wm + ln][kf]);
      const f16x8 a1 = *reinterpret_cast<const f16x8*>(&As[wm + 16 + ln][kf]);
      const f16x8 b0 = *reinterpret_cast<const f16x8*>(&Bs[wn + ln][kf]);
      const f16x8 b1 = *reinterpret_cast<const f16x8*>(&Bs[wn + 16 + ln][kf]);
      acc[0][0] = __builtin_amdgcn_mfma_f32_16x16x32_f16(a0, b0, acc[0][0], 0, 0, 0);
      acc[0][1] = __builtin_amdgcn_mfma_f32_16x16x32_f16(a0, b1, acc[0][1], 0, 0, 0);
      acc[1][0] = __builtin_amdgcn_mfma_f32_16x16x32_f16(a1, b0, acc[1][0], 0, 0, 0);
      acc[1][1] = __builtin_amdgcn_mfma_f32_16x16x32_f16(a1, b1, acc[1][1], 0, 0, 0);
    }

    // ---- epilogue for this o-tile ----
#pragma unroll
    for (int i = 0; i < 2; ++i) {
      const int ob = o0 + wm + 16 * i + quad * 4;
#pragma unroll
      for (int j = 0; j < 2; ++j) {
        const int t = t0 + wn + 16 * j + ln;
        if (t >= NT) continue;
#pragma unroll
        for (int r = 0; r < 4; ++r) {
          const int o = ob + r;
          if (o < NO) oB[(size_t)o * NT + t] = acc[i][j][r];
        }
      }
    }
    __syncthreads();  // all waves done reading As before next o-tile restages
  }
}

extern "C" void kernel_launch(void* const* d_in, const int* in_sizes, int n_in,
                              void* d_out, int out_size, void* d_ws, size_t ws_size,
                              hipStream_t stream) {
  const float* brain = (const float*)d_in[0];   // [32,273,3000]
  const float* layout = (const float*)d_in[1];  // [32,273,2]
  const float* heads = (const float*)d_in[2];   // [270,2048]
  for (int i = 0; i < n_in; ++i) {
    if (in_sizes[i] == NB * NC * NT) brain = (const float*)d_in[i];
    else if (in_sizes[i] == NB * NC * 2) layout = (const float*)d_in[i];
    else if (in_sizes[i] == NO * ND) heads = (const float*)d_in[i];
  }
  float* out = (float*)d_out;  // [32,270,3000]

  float* scores = (float*)((char*)d_ws + S_OFF);     // [NB][NO][NC]
  _Float16* wq = (_Float16*)((char*)d_ws + W_OFF);   // [NB][NO][CP]
  _Float16* hh = (_Float16*)((char*)d_ws + H_OFF);   // [NO][ND]

  heads_cvt_kernel<<<NO, 256, 0, stream>>>(heads, hh);
  scores_kernel<<<800, 256, 0, stream>>>(hh, layout, scores);
  softmax_kernel<<<(NB * NO) / 4, 256, 0, stream>>>(scores, wq);
  out_kernel<<<dim3(47, NB), 256, 0, stream>>>(wq, brain, out);
}

// Round 3
// 282.306 us; speedup vs baseline: 1.0284x; 1.0284x over previous
//
#include <hip/hip_runtime.h>
#include <hip/hip_bf16.h>
#include <hip/hip_fp16.h>

// SpatialAttention: B=32, C=273, T=3000, O=270, D=2048. fp32 in, fp32 out.
#define NB 32
#define NC 273
#define NT 3000
#define NO 270
#define ND 2048
#define CP 288  // C padded to 9*32 for out-GEMM K dimension

typedef _Float16 f16x8 __attribute__((ext_vector_type(8)));
typedef float f32x4 __attribute__((ext_vector_type(4)));

// Workspace layout (bytes):
//   [55296000, 64,730,880)  scores float   [NB][NO][NC]
//   [64730880, 69,707,520)  W     _Float16 [NB][NO][CP]  (softmaxed weights, zero-padded)
//   [69707520, 70,813,440)  headsh _Float16 [NO][ND]
#define S_OFF 55296000UL
#define W_OFF 64730880UL
#define H_OFF 69707520UL

__device__ __forceinline__ unsigned short f2h_bits(float f) {
  _Float16 h = (_Float16)f;
  unsigned short u;
  __builtin_memcpy(&u, &h, 2);
  return u;
}

// ---------------------------------------------------------------------------
// heads fp32 -> fp16. 270 blocks x 256 thr x 8 elems (exact).
// ---------------------------------------------------------------------------
__global__ void heads_cvt_kernel(const float* __restrict__ heads,
                                 _Float16* __restrict__ hh) {
  const size_t idx = ((size_t)blockIdx.x * 256 + threadIdx.x) * 8;
  const float4 a = *reinterpret_cast<const float4*>(heads + idx);
  const float4 c = *reinterpret_cast<const float4*>(heads + idx + 4);
  f16x8 v;
  v[0] = (_Float16)a.x; v[1] = (_Float16)a.y; v[2] = (_Float16)a.z; v[3] = (_Float16)a.w;
  v[4] = (_Float16)c.x; v[5] = (_Float16)c.y; v[6] = (_Float16)c.z; v[7] = (_Float16)c.w;
  *reinterpret_cast<f16x8*>(hh + idx) = v;
}

// ---------------------------------------------------------------------------
// scores[b,o,c] = sum_d heads[o,d]*emb[b,c,d], with the emb B-tile GENERATED
// in-register (phase naturally in revolutions -> fract + v_sin; cos folded
// as +0.25 rev). Tile 64(o) x 64(c), K-step 64, 4 waves 2x2.
// grid = 800 (5 c-tiles x 5 o-tiles x 32 b)
// ---------------------------------------------------------------------------
__global__ void scores_kernel(const _Float16* __restrict__ hh,
                              const float* __restrict__ layout,
                              float* __restrict__ scores) {
  __shared__ _Float16 As[64][72];
  __shared__ _Float16 Bs[64][72];
  const int gid = blockIdx.x;
  const int tid = threadIdx.x;
  const int b = gid / 25;
  const int rem = gid % 25;
  const int o0 = (rem / 5) * 64;
  const int c0 = (rem % 5) * 64;
  const int lane = tid & 63, w = tid >> 6;
  const int wm = (w >> 1) * 32, wn = (w & 1) * 32;
  const int ln = lane & 15, quad = lane >> 4;
  const int sr = tid >> 2;        // staging row 0..63 (o for A, c for B)
  const int sk = (tid & 3) * 16;  // k-chunk offset (halves)

  // Per-thread channel position for B-tile generation.
  const int ch = c0 + sr;
  float px = 0.f, py = 0.f;
  if (ch < NC) {
    const float inv = 1.0f / 1.2f;
    const float* lp = layout + ((size_t)b * NC + ch) * 2;
    px = (lp[0] + 0.1f) * inv;
    py = (lp[1] + 0.1f) * inv;
  }

  f32x4 acc[2][2] = {};

  for (int k0 = 0; k0 < ND; k0 += 64) {
    {  // A-tile staging (heads fp16, L2-resident)
      const int o = o0 + sr;
      uint4 u0 = {0, 0, 0, 0}, u1 = {0, 0, 0, 0};
      if (o < NO) {
        const uint4* p = reinterpret_cast<const uint4*>(hh + (size_t)o * ND + k0 + sk);
        u0 = p[0]; u1 = p[1];
      }
      *reinterpret_cast<uint4*>(&As[sr][sk]) = u0;
      *reinterpret_cast<uint4*>(&As[sr][sk + 8]) = u1;
    }
    {  // B-tile generation: 16 consecutive k share i; base + py*s walks j.
      const int kg = k0 + sk;      // multiple of 16
      const int dd = kg & 1023;    // multiple of 16
      const float base = px * (float)(dd >> 5) + py * (float)(dd & 31)
                       + ((kg < 1024) ? 0.0f : 0.25f);
      f16x8 h0, h1;
#pragma unroll
      for (int s = 0; s < 8; ++s) {
        float ph = base + py * (float)s;
        ph -= floorf(ph);
        h0[s] = (_Float16)__builtin_amdgcn_sinf(ph);
      }
#pragma unroll
      for (int s = 0; s < 8; ++s) {
        float ph = base + py * (float)(s + 8);
        ph -= floorf(ph);
        h1[s] = (_Float16)__builtin_amdgcn_sinf(ph);
      }
      *reinterpret_cast<f16x8*>(&Bs[sr][sk]) = h0;
      *reinterpret_cast<f16x8*>(&Bs[sr][sk + 8]) = h1;
    }
    __syncthreads();
#pragma unroll
    for (int ks = 0; ks < 64; ks += 32) {
      const int kf = ks + quad * 8;
      const f16x8 a0 = *reinterpret_cast<const f16x8*>(&As[wm + ln][kf]);
      const f16x8 a1 = *reinterpret_cast<const f16x8*>(&As[wm + 16 + ln][kf]);
      const f16x8 b0 = *reinterpret_cast<const f16x8*>(&Bs[wn + ln][kf]);
      const f16x8 b1 = *reinterpret_cast<const f16x8*>(&Bs[wn + 16 + ln][kf]);
      acc[0][0] = __builtin_amdgcn_mfma_f32_16x16x32_f16(a0, b0, acc[0][0], 0, 0, 0);
      acc[0][1] = __builtin_amdgcn_mfma_f32_16x16x32_f16(a0, b1, acc[0][1], 0, 0, 0);
      acc[1][0] = __builtin_amdgcn_mfma_f32_16x16x32_f16(a1, b0, acc[1][0], 0, 0, 0);
      acc[1][1] = __builtin_amdgcn_mfma_f32_16x16x32_f16(a1, b1, acc[1][1], 0, 0, 0);
    }
    __syncthreads();
  }

  float* sB = scores + (size_t)b * NO * NC;
#pragma unroll
  for (int i = 0; i < 2; ++i) {
    const int ob = o0 + wm + 16 * i + quad * 4;
#pragma unroll
    for (int j = 0; j < 2; ++j) {
      const int cc = c0 + wn + 16 * j + ln;
      if (cc >= NC) continue;
#pragma unroll
      for (int r = 0; r < 4; ++r) {
        const int o = ob + r;
        if (o < NO) sB[(size_t)o * NC + cc] = acc[i][j][r];
      }
    }
  }
}

// ---------------------------------------------------------------------------
// Row softmax over C=273, fp32 in -> fp16 weights out, zero-padded to CP=288.
// One wave per (b,o) row. grid = 8640/4, block 256.
// ---------------------------------------------------------------------------
__global__ void softmax_kernel(const float* __restrict__ sc,
                               _Float16* __restrict__ wq) {
  const int row = blockIdx.x * 4 + (threadIdx.x >> 6);
  const int lane = threadIdx.x & 63;
  const float* p = sc + (size_t)row * NC;
  _Float16* q = wq + (size_t)row * CP;
  float v[5];
  float m = -3.0e38f;
#pragma unroll
  for (int k = 0; k < 5; ++k) {
    const int c = lane + k * 64;
    v[k] = (c < NC) ? p[c] : -3.0e38f;
    m = fmaxf(m, v[k]);
  }
#pragma unroll
  for (int off = 32; off > 0; off >>= 1) m = fmaxf(m, __shfl_xor(m, off));
  float s = 0.f;
#pragma unroll
  for (int k = 0; k < 5; ++k) {
    v[k] = expf(v[k] - m);
    s += v[k];
  }
#pragma unroll
  for (int off = 32; off > 0; off >>= 1) s += __shfl_xor(s, off);
  const float r = 1.0f / s;
#pragma unroll
  for (int k = 0; k < 5; ++k) {
    const int c = lane + k * 64;
    if (c < NC) q[c] = (_Float16)(v[k] * r);
    else if (c < CP) q[c] = (_Float16)0.f;
  }
}

// ---------------------------------------------------------------------------
// out[b,o,t] = sum_c W[b,o,c]*brain[b,c,t], brain read DIRECTLY.
// Per block (b, 64-t slab):
//   1) stage Bs[t][c] fp16 via f32 tile (9 c-chunks of 32): coalesced float4
//      reads -> tile[32][68] (conflict-free writes & reads) -> pack 8 halves
//      -> ds_write_b128 into Bs rows (pitch 148 dw = 4 mod 8: each 8-lane
//      clock group of a b128 write covers all 32 banks -> conflict-free).
//   2) o-loop, NO LDS for W: A-fragments are 16B contiguous global loads from
//      L2-resident W[b] (per K-step a wave touches exactly 16 x 64B lines).
//      ZERO barriers after staging -- waves run free.
// LDS 46.6 KB -> 3 blocks/CU. grid = (47 t-slabs, 32 b).
// ---------------------------------------------------------------------------
#define TS 64

__global__ __launch_bounds__(256) void out_kernel(
    const _Float16* __restrict__ wq,
    const float* __restrict__ brain,
    float* __restrict__ out) {
  __shared__ _Float16 Bs[TS][296];
  __shared__ float tile[32][68];
  const int b = blockIdx.y;
  const int t0 = blockIdx.x * TS;
  const int tid = threadIdx.x;
  const int lane = tid & 63, w = tid >> 6;
  const int om = (w >> 1) * 32, tn = (w & 1) * 32;
  const int ln = lane & 15, quad = lane >> 4;

  // ---- stage Bs: 9 chunks of 32 channels ----
  const int cl = tid >> 3;        // chunk-local c row 0..31
  const int tq = (tid & 7) * 4;   // t offset 0..28 (two float4: tq, tq+32)
  const int tt = tid & 63;        // transpose-phase t (wave-local 0..63)
  const int cg = tid >> 6;        // transpose-phase c-group 0..3
  for (int p = 0; p < 9; ++p) {
    const int c = p * 32 + cl;
    float4 v0 = {0.f, 0.f, 0.f, 0.f}, v1 = v0;
    if (c < NC) {
      const float* src = brain + ((size_t)b * NC + c) * NT + t0 + tq;
      const int tb = t0 + tq;
      if (tb + 35 < NT) {
        v0 = *reinterpret_cast<const float4*>(src);
        v1 = *reinterpret_cast<const float4*>(src + 32);
      } else {
        if (tb + 0 < NT) v0.x = src[0];
        if (tb + 1 < NT) v0.y = src[1];
        if (tb + 2 < NT) v0.z = src[2];
        if (tb + 3 < NT) v0.w = src[3];
        if (tb + 32 < NT) v1.x = src[32];
        if (tb + 33 < NT) v1.y = src[33];
        if (tb + 34 < NT) v1.z = src[34];
        if (tb + 35 < NT) v1.w = src[35];
      }
    }
    *reinterpret_cast<float4*>(&tile[cl][tq]) = v0;
    *reinterpret_cast<float4*>(&tile[cl][tq + 32]) = v1;
    __syncthreads();
    {
      unsigned short h[8];
#pragma unroll
      for (int s = 0; s < 8; ++s) h[s] = f2h_bits(tile[cg * 8 + s][tt]);
      uint4 u;
      u.x = (unsigned)h[0] | ((unsigned)h[1] << 16);
      u.y = (unsigned)h[2] | ((unsigned)h[3] << 16);
      u.z = (unsigned)h[4] | ((unsigned)h[5] << 16);
      u.w = (unsigned)h[6] | ((unsigned)h[7] << 16);
      *reinterpret_cast<uint4*>(&Bs[tt][p * 32 + cg * 8]) = u;
    }
    __syncthreads();
  }

  const _Float16* Wb = wq + (size_t)b * NO * CP;
  float* oB = out + (size_t)b * NO * NT;
  const int tA = tn + ln;
  const int tB = tn + 16 + ln;

  for (int ot = 0; ot < 5; ++ot) {
    const int o0 = ot * 64;
    // Clamp A rows (o-pad 270..319 duplicates row 269; outputs discarded).
    int ra = o0 + om + ln;      if (ra > NO - 1) ra = NO - 1;
    int rb = o0 + om + 16 + ln; if (rb > NO - 1) rb = NO - 1;
    const _Float16* pA0 = Wb + (size_t)ra * CP + quad * 8;
    const _Float16* pA1 = Wb + (size_t)rb * CP + quad * 8;

    f32x4 acc[2][2] = {};
#pragma unroll
    for (int s = 0; s < 9; ++s) {
      const int kf = s * 32;
      const f16x8 a0 = *reinterpret_cast<const f16x8*>(pA0 + kf);
      const f16x8 a1 = *reinterpret_cast<const f16x8*>(pA1 + kf);
      const f16x8 b0 = *reinterpret_cast<const f16x8*>(&Bs[tA][kf + quad * 8]);
      const f16x8 b1 = *reinterpret_cast<const f16x8*>(&Bs[tB][kf + quad * 8]);
      acc[0][0] = __builtin_amdgcn_mfma_f32_16x16x32_f16(a0, b0, acc[0][0], 0, 0, 0);
      acc[0][1] = __builtin_amdgcn_mfma_f32_16x16x32_f16(a0, b1, acc[0][1], 0, 0, 0);
      acc[1][0] = __builtin_amdgcn_mfma_f32_16x16x32_f16(a1, b0, acc[1][0], 0, 0, 0);
      acc[1][1] = __builtin_amdgcn_mfma_f32_16x16x32_f16(a1, b1, acc[1][1], 0, 0, 0);
    }

    // Epilogue for this o-tile (no barrier needed; Bs is read-only now).
#pragma unroll
    for (int i = 0; i < 2; ++i) {
      const int ob = o0 + om + 16 * i + quad * 4;
#pragma unroll
      for (int j = 0; j < 2; ++j) {
        const int t = t0 + tn + 16 * j + ln;
        if (t >= NT) continue;
#pragma unroll
        for (int r = 0; r < 4; ++r) {
          const int o = ob + r;
          if (o < NO) oB[(size_t)o * NT + t] = acc[i][j][r];
        }
      }
    }
  }
}

extern "C" void kernel_launch(void* const* d_in, const int* in_sizes, int n_in,
                              void* d_out, int out_size, void* d_ws, size_t ws_size,
                              hipStream_t stream) {
  const float* brain = (const float*)d_in[0];   // [32,273,3000]
  const float* layout = (const float*)d_in[1];  // [32,273,2]
  const float* heads = (const float*)d_in[2];   // [270,2048]
  for (int i = 0; i < n_in; ++i) {
    if (in_sizes[i] == NB * NC * NT) brain = (const float*)d_in[i];
    else if (in_sizes[i] == NB * NC * 2) layout = (const float*)d_in[i];
    else if (in_sizes[i] == NO * ND) heads = (const float*)d_in[i];
  }
  float* out = (float*)d_out;  // [32,270,3000]

  float* scores = (float*)((char*)d_ws + S_OFF);     // [NB][NO][NC]
  _Float16* wq = (_Float16*)((char*)d_ws + W_OFF);   // [NB][NO][CP]
  _Float16* hh = (_Float16*)((char*)d_ws + H_OFF);   // [NO][ND]

  heads_cvt_kernel<<<NO, 256, 0, stream>>>(heads, hh);
  scores_kernel<<<800, 256, 0, stream>>>(hh, layout, scores);
  softmax_kernel<<<(NB * NO) / 4, 256, 0, stream>>>(scores, wq);
  out_kernel<<<dim3(47, NB), 256, 0, stream>>>(wq, brain, out);
}

// Round 4
// 279.527 us; speedup vs baseline: 1.0386x; 1.0099x over previous
//
#include <hip/hip_runtime.h>
#include <hip/hip_bf16.h>
#include <hip/hip_fp16.h>

// SpatialAttention: B=32, C=273, T=3000, O=270, D=2048. fp32 in, fp32 out.
#define NB 32
#define NC 273
#define NT 3000
#define NO 270
#define ND 2048
#define CP 288  // C padded to 9*32 for out-GEMM K dimension

typedef _Float16 f16x8 __attribute__((ext_vector_type(8)));
typedef float f32x4 __attribute__((ext_vector_type(4)));

// Workspace layout (bytes):
//   [55296000, 64,730,880)  scores float   [NB][NO][NC]
//   [64730880, 69,707,520)  W     _Float16 [NB][NO][CP]  (softmaxed weights, zero-padded)
//   [69707520, 70,813,440)  headsh _Float16 [NO][ND]
#define S_OFF 55296000UL
#define W_OFF 64730880UL
#define H_OFF 69707520UL

__device__ __forceinline__ unsigned short f2h_bits(float f) {
  _Float16 h = (_Float16)f;
  unsigned short u;
  __builtin_memcpy(&u, &h, 2);
  return u;
}

// ---------------------------------------------------------------------------
// heads fp32 -> fp16. 270 blocks x 256 thr x 8 elems (exact).
// ---------------------------------------------------------------------------
__global__ void heads_cvt_kernel(const float* __restrict__ heads,
                                 _Float16* __restrict__ hh) {
  const size_t idx = ((size_t)blockIdx.x * 256 + threadIdx.x) * 8;
  const float4 a = *reinterpret_cast<const float4*>(heads + idx);
  const float4 c = *reinterpret_cast<const float4*>(heads + idx + 4);
  f16x8 v;
  v[0] = (_Float16)a.x; v[1] = (_Float16)a.y; v[2] = (_Float16)a.z; v[3] = (_Float16)a.w;
  v[4] = (_Float16)c.x; v[5] = (_Float16)c.y; v[6] = (_Float16)c.z; v[7] = (_Float16)c.w;
  *reinterpret_cast<f16x8*>(hh + idx) = v;
}

// ---------------------------------------------------------------------------
// scores[b,o,c] = sum_d heads[o,d]*emb[b,c,d], with the emb B-tile GENERATED
// in-register (phase naturally in revolutions -> fract + v_sin; cos folded
// as +0.25 rev). Tile 64(o) x 64(c), K-step 64, 4 waves 2x2.
// grid = 800 (5 c-tiles x 5 o-tiles x 32 b)
// ---------------------------------------------------------------------------
__global__ void scores_kernel(const _Float16* __restrict__ hh,
                              const float* __restrict__ layout,
                              float* __restrict__ scores) {
  __shared__ _Float16 As[64][72];
  __shared__ _Float16 Bs[64][72];
  const int gid = blockIdx.x;
  const int tid = threadIdx.x;
  const int b = gid / 25;
  const int rem = gid % 25;
  const int o0 = (rem / 5) * 64;
  const int c0 = (rem % 5) * 64;
  const int lane = tid & 63, w = tid >> 6;
  const int wm = (w >> 1) * 32, wn = (w & 1) * 32;
  const int ln = lane & 15, quad = lane >> 4;
  const int sr = tid >> 2;        // staging row 0..63 (o for A, c for B)
  const int sk = (tid & 3) * 16;  // k-chunk offset (halves)

  // Per-thread channel position for B-tile generation.
  const int ch = c0 + sr;
  float px = 0.f, py = 0.f;
  if (ch < NC) {
    const float inv = 1.0f / 1.2f;
    const float* lp = layout + ((size_t)b * NC + ch) * 2;
    px = (lp[0] + 0.1f) * inv;
    py = (lp[1] + 0.1f) * inv;
  }

  f32x4 acc[2][2] = {};

  for (int k0 = 0; k0 < ND; k0 += 64) {
    {  // A-tile staging (heads fp16, L2-resident)
      const int o = o0 + sr;
      uint4 u0 = {0, 0, 0, 0}, u1 = {0, 0, 0, 0};
      if (o < NO) {
        const uint4* p = reinterpret_cast<const uint4*>(hh + (size_t)o * ND + k0 + sk);
        u0 = p[0]; u1 = p[1];
      }
      *reinterpret_cast<uint4*>(&As[sr][sk]) = u0;
      *reinterpret_cast<uint4*>(&As[sr][sk + 8]) = u1;
    }
    {  // B-tile generation: 16 consecutive k share i; base + py*s walks j.
      const int kg = k0 + sk;      // multiple of 16
      const int dd = kg & 1023;    // multiple of 16
      const float base = px * (float)(dd >> 5) + py * (float)(dd & 31)
                       + ((kg < 1024) ? 0.0f : 0.25f);
      f16x8 h0, h1;
#pragma unroll
      for (int s = 0; s < 8; ++s) {
        float ph = base + py * (float)s;
        ph -= floorf(ph);
        h0[s] = (_Float16)__builtin_amdgcn_sinf(ph);
      }
#pragma unroll
      for (int s = 0; s < 8; ++s) {
        float ph = base + py * (float)(s + 8);
        ph -= floorf(ph);
        h1[s] = (_Float16)__builtin_amdgcn_sinf(ph);
      }
      *reinterpret_cast<f16x8*>(&Bs[sr][sk]) = h0;
      *reinterpret_cast<f16x8*>(&Bs[sr][sk + 8]) = h1;
    }
    __syncthreads();
#pragma unroll
    for (int ks = 0; ks < 64; ks += 32) {
      const int kf = ks + quad * 8;
      const f16x8 a0 = *reinterpret_cast<const f16x8*>(&As[wm + ln][kf]);
      const f16x8 a1 = *reinterpret_cast<const f16x8*>(&As[wm + 16 + ln][kf]);
      const f16x8 b0 = *reinterpret_cast<const f16x8*>(&Bs[wn + ln][kf]);
      const f16x8 b1 = *reinterpret_cast<const f16x8*>(&Bs[wn + 16 + ln][kf]);
      acc[0][0] = __builtin_amdgcn_mfma_f32_16x16x32_f16(a0, b0, acc[0][0], 0, 0, 0);
      acc[0][1] = __builtin_amdgcn_mfma_f32_16x16x32_f16(a0, b1, acc[0][1], 0, 0, 0);
      acc[1][0] = __builtin_amdgcn_mfma_f32_16x16x32_f16(a1, b0, acc[1][0], 0, 0, 0);
      acc[1][1] = __builtin_amdgcn_mfma_f32_16x16x32_f16(a1, b1, acc[1][1], 0, 0, 0);
    }
    __syncthreads();
  }

  float* sB = scores + (size_t)b * NO * NC;
#pragma unroll
  for (int i = 0; i < 2; ++i) {
    const int ob = o0 + wm + 16 * i + quad * 4;
#pragma unroll
    for (int j = 0; j < 2; ++j) {
      const int cc = c0 + wn + 16 * j + ln;
      if (cc >= NC) continue;
#pragma unroll
      for (int r = 0; r < 4; ++r) {
        const int o = ob + r;
        if (o < NO) sB[(size_t)o * NC + cc] = acc[i][j][r];
      }
    }
  }
}

// ---------------------------------------------------------------------------
// Row softmax over C=273, fp32 in -> fp16 weights out, zero-padded to CP=288.
// One wave per (b,o) row. grid = 8640/4, block 256.
// ---------------------------------------------------------------------------
__global__ void softmax_kernel(const float* __restrict__ sc,
                               _Float16* __restrict__ wq) {
  const int row = blockIdx.x * 4 + (threadIdx.x >> 6);
  const int lane = threadIdx.x & 63;
  const float* p = sc + (size_t)row * NC;
  _Float16* q = wq + (size_t)row * CP;
  float v[5];
  float m = -3.0e38f;
#pragma unroll
  for (int k = 0; k < 5; ++k) {
    const int c = lane + k * 64;
    v[k] = (c < NC) ? p[c] : -3.0e38f;
    m = fmaxf(m, v[k]);
  }
#pragma unroll
  for (int off = 32; off > 0; off >>= 1) m = fmaxf(m, __shfl_xor(m, off));
  float s = 0.f;
#pragma unroll
  for (int k = 0; k < 5; ++k) {
    v[k] = expf(v[k] - m);
    s += v[k];
  }
#pragma unroll
  for (int off = 32; off > 0; off >>= 1) s += __shfl_xor(s, off);
  const float r = 1.0f / s;
#pragma unroll
  for (int k = 0; k < 5; ++k) {
    const int c = lane + k * 64;
    if (c < NC) q[c] = (_Float16)(v[k] * r);
    else if (c < CP) q[c] = (_Float16)0.f;
  }
}

// ---------------------------------------------------------------------------
// out[b,o,t] = sum_c W[b,o,c]*brain[b,c,t], brain read DIRECTLY.
// Latency-hiding version of round 3:
//  * staging: 9 c-chunks, register-prefetch chunk p+1 issued BEFORE chunk p's
//    transpose; raw s_barrier + lgkmcnt-only waits so in-flight global loads
//    are NOT drained at barriers (hipcc __syncthreads would drain vmcnt).
//  * o-loop: all 18 A-fragments of an o-tile live in registers (one L2
//    round-trip instead of 9 serialized); next o-tile's A-loads issued right
//    after this tile's MFMAs, hidden under the epilogue stores. No barriers.
// LDS 46.6 KB -> 3 blocks/CU. grid = (47 t-slabs, 32 b).
// ---------------------------------------------------------------------------
#define TS 64

__device__ __forceinline__ void load_a_frags(const _Float16* __restrict__ Wb,
                                             int o0, int om, int ln, int quad,
                                             f16x8* a0f, f16x8* a1f) {
  int ra = o0 + om + ln;      if (ra > NO - 1) ra = NO - 1;
  int rb = o0 + om + 16 + ln; if (rb > NO - 1) rb = NO - 1;
  const _Float16* pA0 = Wb + (size_t)ra * CP + quad * 8;
  const _Float16* pA1 = Wb + (size_t)rb * CP + quad * 8;
#pragma unroll
  for (int s = 0; s < 9; ++s) {
    a0f[s] = *reinterpret_cast<const f16x8*>(pA0 + s * 32);
    a1f[s] = *reinterpret_cast<const f16x8*>(pA1 + s * 32);
  }
}

__global__ __launch_bounds__(256) void out_kernel(
    const _Float16* __restrict__ wq,
    const float* __restrict__ brain,
    float* __restrict__ out) {
  __shared__ _Float16 Bs[TS][296];
  __shared__ float tile[32][68];
  const int b = blockIdx.y;
  const int t0 = blockIdx.x * TS;
  const int tid = threadIdx.x;
  const int lane = tid & 63, w = tid >> 6;
  const int om = (w >> 1) * 32, tn = (w & 1) * 32;
  const int ln = lane & 15, quad = lane >> 4;

  const _Float16* Wb = wq + (size_t)b * NO * CP;

  // Issue first o-tile's A-fragment loads NOW; they land during staging.
  f16x8 a0f[9], a1f[9];
  load_a_frags(Wb, 0, om, ln, quad, a0f, a1f);

  // ---- stage Bs: 9 chunks of 32 channels, 1-deep register prefetch ----
  const int cl = tid >> 3;        // chunk-local c row 0..31
  const int tq = (tid & 7) * 4;   // t offset 0..28 (two float4: tq, tq+32)
  const int tt = tid & 63;        // transpose-phase t (wave-local 0..63)
  const int cg = tid >> 6;        // transpose-phase c-group 0..3

  const int tb = t0 + tq;
  float4 v0 = {0.f, 0.f, 0.f, 0.f}, v1 = v0;
  {  // load chunk 0
    const int c = cl;
    if (c < NC) {
      const float* src = brain + ((size_t)b * NC + c) * NT + tb;
      if (tb + 35 < NT) {
        v0 = *reinterpret_cast<const float4*>(src);
        v1 = *reinterpret_cast<const float4*>(src + 32);
      } else {
        if (tb + 0 < NT) v0.x = src[0];
        if (tb + 1 < NT) v0.y = src[1];
        if (tb + 2 < NT) v0.z = src[2];
        if (tb + 3 < NT) v0.w = src[3];
        if (tb + 32 < NT) v1.x = src[32];
        if (tb + 33 < NT) v1.y = src[33];
        if (tb + 34 < NT) v1.z = src[34];
        if (tb + 35 < NT) v1.w = src[35];
      }
    }
  }

  for (int p = 0; p < 9; ++p) {
    *reinterpret_cast<float4*>(&tile[cl][tq]) = v0;
    *reinterpret_cast<float4*>(&tile[cl][tq + 32]) = v1;
    // prefetch chunk p+1 (stays in flight across the raw barriers below)
    float4 n0 = {0.f, 0.f, 0.f, 0.f}, n1 = n0;
    if (p < 8) {
      const int c = (p + 1) * 32 + cl;
      if (c < NC) {
        const float* src = brain + ((size_t)b * NC + c) * NT + tb;
        if (tb + 35 < NT) {
          n0 = *reinterpret_cast<const float4*>(src);
          n1 = *reinterpret_cast<const float4*>(src + 32);
        } else {
          if (tb + 0 < NT) n0.x = src[0];
          if (tb + 1 < NT) n0.y = src[1];
          if (tb + 2 < NT) n0.z = src[2];
          if (tb + 3 < NT) n0.w = src[3];
          if (tb + 32 < NT) n1.x = src[32];
          if (tb + 33 < NT) n1.y = src[33];
          if (tb + 34 < NT) n1.z = src[34];
          if (tb + 35 < NT) n1.w = src[35];
        }
      }
    }
    asm volatile("s_waitcnt lgkmcnt(0)" ::: "memory");
    __builtin_amdgcn_sched_barrier(0);
    __builtin_amdgcn_s_barrier();
    {  // transpose tile -> Bs (conflict-free; see round-3 analysis)
      unsigned short h[8];
#pragma unroll
      for (int s = 0; s < 8; ++s) h[s] = f2h_bits(tile[cg * 8 + s][tt]);
      uint4 u;
      u.x = (unsigned)h[0] | ((unsigned)h[1] << 16);
      u.y = (unsigned)h[2] | ((unsigned)h[3] << 16);
      u.z = (unsigned)h[4] | ((unsigned)h[5] << 16);
      u.w = (unsigned)h[6] | ((unsigned)h[7] << 16);
      *reinterpret_cast<uint4*>(&Bs[tt][p * 32 + cg * 8]) = u;
    }
    asm volatile("s_waitcnt lgkmcnt(0)" ::: "memory");
    __builtin_amdgcn_sched_barrier(0);
    __builtin_amdgcn_s_barrier();
    v0 = n0; v1 = n1;
  }

  float* oB = out + (size_t)b * NO * NT;
  const int tA = tn + ln;
  const int tB = tn + 16 + ln;

#pragma unroll
  for (int ot = 0; ot < 5; ++ot) {
    const int o0 = ot * 64;
    f32x4 acc[2][2] = {};
#pragma unroll
    for (int s = 0; s < 9; ++s) {
      const int kf = s * 32;
      const f16x8 b0 = *reinterpret_cast<const f16x8*>(&Bs[tA][kf + quad * 8]);
      const f16x8 b1 = *reinterpret_cast<const f16x8*>(&Bs[tB][kf + quad * 8]);
      acc[0][0] = __builtin_amdgcn_mfma_f32_16x16x32_f16(a0f[s], b0, acc[0][0], 0, 0, 0);
      acc[0][1] = __builtin_amdgcn_mfma_f32_16x16x32_f16(a0f[s], b1, acc[0][1], 0, 0, 0);
      acc[1][0] = __builtin_amdgcn_mfma_f32_16x16x32_f16(a1f[s], b0, acc[1][0], 0, 0, 0);
      acc[1][1] = __builtin_amdgcn_mfma_f32_16x16x32_f16(a1f[s], b1, acc[1][1], 0, 0, 0);
    }

    // Issue next o-tile's A-loads; they land under the epilogue stores.
    if (ot < 4) load_a_frags(Wb, o0 + 64, om, ln, quad, a0f, a1f);

    // ---- epilogue for this o-tile (no barriers; Bs is read-only now) ----
#pragma unroll
    for (int i = 0; i < 2; ++i) {
      const int ob = o0 + om + 16 * i + quad * 4;
#pragma unroll
      for (int j = 0; j < 2; ++j) {
        const int t = t0 + tn + 16 * j + ln;
        if (t >= NT) continue;
#pragma unroll
        for (int r = 0; r < 4; ++r) {
          const int o = ob + r;
          if (o < NO) oB[(size_t)o * NT + t] = acc[i][j][r];
        }
      }
    }
  }
}

extern "C" void kernel_launch(void* const* d_in, const int* in_sizes, int n_in,
                              void* d_out, int out_size, void* d_ws, size_t ws_size,
                              hipStream_t stream) {
  const float* brain = (const float*)d_in[0];   // [32,273,3000]
  const float* layout = (const float*)d_in[1];  // [32,273,2]
  const float* heads = (const float*)d_in[2];   // [270,2048]
  for (int i = 0; i < n_in; ++i) {
    if (in_sizes[i] == NB * NC * NT) brain = (const float*)d_in[i];
    else if (in_sizes[i] == NB * NC * 2) layout = (const float*)d_in[i];
    else if (in_sizes[i] == NO * ND) heads = (const float*)d_in[i];
  }
  float* out = (float*)d_out;  // [32,270,3000]

  float* scores = (float*)((char*)d_ws + S_OFF);     // [NB][NO][NC]
  _Float16* wq = (_Float16*)((char*)d_ws + W_OFF);   // [NB][NO][CP]
  _Float16* hh = (_Float16*)((char*)d_ws + H_OFF);   // [NO][ND]

  heads_cvt_kernel<<<NO, 256, 0, stream>>>(heads, hh);
  scores_kernel<<<800, 256, 0, stream>>>(hh, layout, scores);
  softmax_kernel<<<(NB * NO) / 4, 256, 0, stream>>>(scores, wq);
  out_kernel<<<dim3(47, NB), 256, 0, stream>>>(wq, brain, out);
}